// Round 4
// baseline (183.357 us; speedup 1.0000x reference)
//
#include <hip/hip_runtime.h>

#define N_ARMS   2048
#define NTHREADS 256
#define EPB      8      // elements per thread: 256*8 = 2048
#define N_ITER   200
#define KBUDGET  40.0f

// Cramer solve of 3x3 A x = b. Rows: (a0*,a1*,a2*).
__device__ __forceinline__ void solve3(
    float a00, float a01, float a02,
    float a10, float a11, float a12,
    float a20, float a21, float a22,
    float b0, float b1, float b2,
    float& x0, float& x1, float& x2)
{
    float M00 = a11 * a22 - a12 * a21;
    float M01 = a10 * a22 - a12 * a20;
    float M02 = a10 * a21 - a11 * a20;
    float det = a00 * M00 - a01 * M01 + a02 * M02;
    float inv = 1.0f / det;
    float N0  = b1 * a22 - a12 * b2;   // minor with b in col
    float N1  = b1 * a21 - a11 * b2;
    float N2  = a10 * b2 - b1 * a20;
    x0 = (b0 * M00 - a01 * N0 + a02 * N1) * inv;
    x1 = (a00 * N0 - b0 * M01 + a02 * N2) * inv;
    x2 = (a00 * (a11 * b2 - b1 * a21) - a01 * N2 + b0 * M02) * inv;
}

__global__ __launch_bounds__(NTHREADS, 1) void rmab_kernel(
    const float* __restrict__ T, const int* __restrict__ state,
    float* __restrict__ out)
{
    const int b    = blockIdx.x;
    const int tid  = threadIdx.x;
    const int lane = tid & 63;
    const int wid  = tid >> 6;
    const float gd      = 0.99f;
    const float inv_eps = 100.0f;

    const float* Tb  = T + (size_t)b * N_ARMS * 8;
    const int*   stb = state + (size_t)b * N_ARMS;

    float c0r[EPB], c1r[EPB];       // raw (unnormalized) cost columns
    float t_arr[EPB];               // (C1 - C0)/eps after normalization
    float sig[EPB];
    float cmax_local = 0.0f;

    #pragma unroll
    for (int e = 0; e < EPB; ++e) {
        int i = e * NTHREADS + tid;
        const float4* p = (const float4*)(Tb + (size_t)i * 8);
        float4 T0 = p[0];   // t000 t001 t010 t011  (s=0)
        float4 T1 = p[1];   // t100 t101 t110 t111  (s=1)
        int st = stb[i];
        bool s1 = (st != 0);

        // r1 = {1, g*t000-1, g*t001}; r2 = {0, g*t010-1, g*t011}
        // r3 = {1, g*t100, g*t101-1}; r4 = {0, g*t110, g*t111-1}
        float r1y = gd * T0.x - 1.0f, r1z = gd * T0.y;
        float r2y = gd * T0.z - 1.0f, r2z = gd * T0.w;
        float r3y = gd * T1.x,        r3z = gd * T1.y - 1.0f;
        float r4y = gd * T1.z,        r4z = gd * T1.w - 1.0f;

        // state0: A1={r1,r2,r3}, A2={r1,r2,r4}, b={0,0,-1}
        // state1: A1={r3,r4,r1}, A2={r3,r4,r2}, b={-1,-1,0}
        float a01 = s1 ? r3y : r1y, a02 = s1 ? r3z : r1z;   // row0 (x=1)
        float a11 = s1 ? r4y : r2y, a12 = s1 ? r4z : r2z;   // row1 (x=0)
        float c21 = s1 ? r1y : r3y, c22 = s1 ? r1z : r3z;   // row2 of A1 (x=1)
        float d21 = s1 ? r2y : r4y, d22 = s1 ? r2z : r4z;   // row2 of A2 (x=0)
        float bv0 = s1 ? -1.0f : 0.0f;
        float bv1 = s1 ? -1.0f : 0.0f;
        float bv2 = s1 ?  0.0f : -1.0f;

        float x0, x1, x2;
        solve3(1.0f, a01, a02,  0.0f, a11, a12,  1.0f, c21, c22,
               bv0, bv1, bv2, x0, x1, x2);
        float y0, y1u, y2u;
        solve3(1.0f, a01, a02,  0.0f, a11, a12,  0.0f, d21, d22,
               bv0, bv1, bv2, y0, y1u, y2u);

        // m condition, reference-faithful operand order
        float p0 = s1 ? T0.x : T1.x;
        float p1 = s1 ? T0.y : T1.y;
        float q0 = s1 ? T0.z : T1.z;
        float q1 = s1 ? T0.w : T1.w;
        float base = s1 ? 0.0f : 1.0f;
        float lhs = x0 + base + gd * (p0 * x1 + p1 * x2);
        float rhs = base + gd * (q0 * x1 + q1 * x2);
        float w  = (lhs >= rhs) ? x0 : y0;

        float sc = -w;                       // score = -W_state
        float c0 = sc * sc;                  // (s - 0)^2
        float c1 = (sc - 1.0f) * (sc - 1.0f);// (s - 1)^2
        c0r[e] = c0; c1r[e] = c1;
        cmax_local = fmaxf(cmax_local, fmaxf(c0, c1));
    }

    // ---- block max reduce for C normalization ----
    __shared__ float red[2][4];
    float m = cmax_local;
    #pragma unroll
    for (int o = 1; o < 64; o <<= 1) m = fmaxf(m, __shfl_xor(m, o));
    if (lane == 0) red[0][wid] = m;
    __syncthreads();
    float Cm = fmaxf(fmaxf(red[0][0], red[0][1]), fmaxf(red[0][2], red[0][3]));
    __syncthreads();

    #pragma unroll
    for (int e = 0; e < EPB; ++e) {
        float C0n = c0r[e] / Cm;
        float C1n = c1r[e] / Cm;
        t_arr[e] = (C1n - C0n) * inv_eps;
    }

    // ---- collapsed Sinkhorn: u' = u + log(40(2048-S)/(2008 S)), S = sum sigmoid(u+t) ----
    float u = 0.0f;
    float S = 0.0f;
    for (int it = 0; it < N_ITER; ++it) {
        float local = 0.0f;
        #pragma unroll
        for (int e = 0; e < EPB; ++e) {
            float x = u + t_arr[e];
            float sg = __fdividef(1.0f, 1.0f + __expf(-x));  // sigmoid; saturates cleanly
            sig[e] = sg;
            local += sg;
        }
        #pragma unroll
        for (int o = 1; o < 64; o <<= 1) local += __shfl_xor(local, o);
        int buf = it & 1;
        if (lane == 0) red[buf][wid] = local;
        __syncthreads();
        S = red[buf][0] + red[buf][1] + red[buf][2] + red[buf][3];
        if (it < N_ITER - 1) {
            u += __logf(__fdividef(KBUDGET * (2048.0f - S), 2008.0f * S));
        }
        // note: no second barrier needed — double-buffered red[]
    }

    // out_i = n * Gamma_i0 = (40/S) * sigmoid(u_199 + t_i)
    float scale = KBUDGET / S;
    float* ob = out + (size_t)b * N_ARMS;
    #pragma unroll
    for (int e = 0; e < EPB; ++e) {
        ob[e * NTHREADS + tid] = scale * sig[e];
    }
}

extern "C" void kernel_launch(void* const* d_in, const int* in_sizes, int n_in,
                              void* d_out, int out_size, void* d_ws, size_t ws_size,
                              hipStream_t stream) {
    const float* T     = (const float*)d_in[0];
    const int*   state = (const int*)d_in[1];
    float*       out   = (float*)d_out;
    int B = in_sizes[1] / N_ARMS;   // state is [B, N]
    rmab_kernel<<<dim3(B), dim3(NTHREADS), 0, stream>>>(T, state, out);
}

// Round 5
// 145.623 us; speedup vs baseline: 1.2591x; 1.2591x over previous
//
#include <hip/hip_runtime.h>

#define N_ARMS   2048
#define NTHREADS 256
#define EPB      8      // elements per thread: 256*8 = 2048
#define N_ITER   200
#define KBUDGET  40.0f

// ---------- DPP wave64 reductions (VALU-only; avoids LDS-pipe ds_swizzle/bpermute,
// whose ~120cy single-outstanding latency x6 dominated the v0 iteration chain) ----------
template <int CTRL>
__device__ __forceinline__ float dpp_mov0(float x) {
    // v_mov_b32_dpp with bound_ctrl: invalid-source lanes read 0
    return __int_as_float(__builtin_amdgcn_update_dpp(0, __float_as_int(x), CTRL, 0xf, 0xf, true));
}
__device__ __forceinline__ float wave_sum64(float x) {
    x += dpp_mov0<0x111>(x);   // row_shr:1
    x += dpp_mov0<0x112>(x);   // row_shr:2
    x += dpp_mov0<0x114>(x);   // row_shr:4
    x += dpp_mov0<0x118>(x);   // row_shr:8  -> lanes 15,31,47,63 hold row sums
    x += dpp_mov0<0x142>(x);   // row_bcast:15
    x += dpp_mov0<0x143>(x);   // row_bcast:31 -> lane 63 holds wave total
    return __int_as_float(__builtin_amdgcn_readlane(__float_as_int(x), 63));
}
__device__ __forceinline__ float wave_max64(float x) {
    // 0-fill is safe: inputs are squared costs (>= 0)
    x = fmaxf(x, dpp_mov0<0x111>(x));
    x = fmaxf(x, dpp_mov0<0x112>(x));
    x = fmaxf(x, dpp_mov0<0x114>(x));
    x = fmaxf(x, dpp_mov0<0x118>(x));
    x = fmaxf(x, dpp_mov0<0x142>(x));
    x = fmaxf(x, dpp_mov0<0x143>(x));
    return __int_as_float(__builtin_amdgcn_readlane(__float_as_int(x), 63));
}

// Cramer solve of 3x3 A x = b. Rows: (a0*,a1*,a2*).
__device__ __forceinline__ void solve3(
    float a00, float a01, float a02,
    float a10, float a11, float a12,
    float a20, float a21, float a22,
    float b0, float b1, float b2,
    float& x0, float& x1, float& x2)
{
    float M00 = a11 * a22 - a12 * a21;
    float M01 = a10 * a22 - a12 * a20;
    float M02 = a10 * a21 - a11 * a20;
    float det = a00 * M00 - a01 * M01 + a02 * M02;
    float inv = 1.0f / det;
    float N0  = b1 * a22 - a12 * b2;
    float N1  = b1 * a21 - a11 * b2;
    float N2  = a10 * b2 - b1 * a20;
    x0 = (b0 * M00 - a01 * N0 + a02 * N1) * inv;
    x1 = (a00 * N0 - b0 * M01 + a02 * N2) * inv;
    x2 = (a00 * (a11 * b2 - b1 * a21) - a01 * N2 + b0 * M02) * inv;
}

__global__ __launch_bounds__(NTHREADS, 1) void rmab_kernel(
    const float* __restrict__ T, const int* __restrict__ state,
    float* __restrict__ out)
{
    const int b    = blockIdx.x;
    const int tid  = threadIdx.x;
    const int lane = tid & 63;
    const int wid  = tid >> 6;
    const float gd = 0.99f;
    // sigmoid in exp2 domain: sigma(x) = 1/(1 + 2^(-x*log2e)); fold 1/eps and log2e into t
    const float K_T = 100.0f * 1.4426950408889634f;  // inv_eps * log2(e)

    const float* Tb  = T + (size_t)b * N_ARMS * 8;
    const int*   stb = state + (size_t)b * N_ARMS;

    float c0r[EPB], c1r[EPB];
    float mt[EPB];                  // -(C1n - C0n) * K_T  (negated, log2-scaled)
    float sig[EPB];
    float cmax_local = 0.0f;

    #pragma unroll
    for (int e = 0; e < EPB; ++e) {
        int i = e * NTHREADS + tid;
        const float4* p = (const float4*)(Tb + (size_t)i * 8);
        float4 T0 = p[0];   // t000 t001 t010 t011  (s=0)
        float4 T1 = p[1];   // t100 t101 t110 t111  (s=1)
        int st = stb[i];
        bool s1 = (st != 0);

        float r1y = gd * T0.x - 1.0f, r1z = gd * T0.y;
        float r2y = gd * T0.z - 1.0f, r2z = gd * T0.w;
        float r3y = gd * T1.x,        r3z = gd * T1.y - 1.0f;
        float r4y = gd * T1.z,        r4z = gd * T1.w - 1.0f;

        // state0: A1={r1,r2,r3}, A2={r1,r2,r4}, b={0,0,-1}
        // state1: A1={r3,r4,r1}, A2={r3,r4,r2}, b={-1,-1,0}
        float a01 = s1 ? r3y : r1y, a02 = s1 ? r3z : r1z;
        float a11 = s1 ? r4y : r2y, a12 = s1 ? r4z : r2z;
        float c21 = s1 ? r1y : r3y, c22 = s1 ? r1z : r3z;
        float d21 = s1 ? r2y : r4y, d22 = s1 ? r2z : r4z;
        float bv0 = s1 ? -1.0f : 0.0f;
        float bv1 = s1 ? -1.0f : 0.0f;
        float bv2 = s1 ?  0.0f : -1.0f;

        float x0, x1, x2;
        solve3(1.0f, a01, a02,  0.0f, a11, a12,  1.0f, c21, c22,
               bv0, bv1, bv2, x0, x1, x2);
        float y0, y1u, y2u;
        solve3(1.0f, a01, a02,  0.0f, a11, a12,  0.0f, d21, d22,
               bv0, bv1, bv2, y0, y1u, y2u);

        float p0 = s1 ? T0.x : T1.x;
        float p1 = s1 ? T0.y : T1.y;
        float q0 = s1 ? T0.z : T1.z;
        float q1 = s1 ? T0.w : T1.w;
        float base = s1 ? 0.0f : 1.0f;
        float lhs = x0 + base + gd * (p0 * x1 + p1 * x2);
        float rhs = base + gd * (q0 * x1 + q1 * x2);
        float w  = (lhs >= rhs) ? x0 : y0;

        float sc = -w;
        float c0 = sc * sc;
        float c1 = (sc - 1.0f) * (sc - 1.0f);
        c0r[e] = c0; c1r[e] = c1;
        cmax_local = fmaxf(cmax_local, fmaxf(c0, c1));
    }

    // ---- block max reduce for C normalization (DPP in-wave, LDS across waves) ----
    __shared__ __align__(16) float red[2][4];
    float wm = wave_max64(cmax_local);
    if (lane == 63) red[0][wid] = wm;
    __syncthreads();
    float Cm = fmaxf(fmaxf(red[0][0], red[0][1]), fmaxf(red[0][2], red[0][3]));
    __syncthreads();

    float invCm = K_T / Cm;
    #pragma unroll
    for (int e = 0; e < EPB; ++e) {
        mt[e] = (c0r[e] - c1r[e]) * invCm;   // = -(C1n - C0n)*K_T
    }

    // ---- collapsed Sinkhorn in log2 domain:
    //   S = sum_i 1/(1 + 2^(mt_i - u2)),  u2 += log2((2048-S)/S) + log2(40/2008)
    const float DU_C = -5.6496276f;          // log2(40/2008)
    float u2 = 0.0f;
    float S  = 0.0f;
    for (int it = 0; it < N_ITER; ++it) {
        float local = 0.0f;
        #pragma unroll
        for (int e = 0; e < EPB; ++e) {
            float ex = __builtin_amdgcn_exp2f(mt[e] - u2);   // 2^(-x)
            float sg = __frcp_rn(1.0f + ex);
            sig[e] = sg;
            local += sg;
        }
        float wsum = wave_sum64(local);
        int buf = it & 1;
        if (lane == 63) red[buf][wid] = wsum;
        __syncthreads();
        float4 pr = *(const float4*)red[buf];
        S = (pr.x + pr.y) + (pr.z + pr.w);
        if (it < N_ITER - 1) {
            u2 += __log2f(__fdividef(2048.0f - S, S)) + DU_C;
        }
        // no second barrier: red[] is double-buffered (next write to this buf
        // is 2 iterations away, separated by 2 barriers)
    }

    // out_i = n * Gamma_i0 = (40/S) * sigmoid_i  at the final iterate
    float scale = KBUDGET / S;
    float* ob = out + (size_t)b * N_ARMS;
    #pragma unroll
    for (int e = 0; e < EPB; ++e) {
        ob[e * NTHREADS + tid] = scale * sig[e];
    }
}

extern "C" void kernel_launch(void* const* d_in, const int* in_sizes, int n_in,
                              void* d_out, int out_size, void* d_ws, size_t ws_size,
                              hipStream_t stream) {
    const float* T     = (const float*)d_in[0];
    const int*   state = (const int*)d_in[1];
    float*       out   = (float*)d_out;
    int B = in_sizes[1] / N_ARMS;   // state is [B, N]
    rmab_kernel<<<dim3(B), dim3(NTHREADS), 0, stream>>>(T, state, out);
}

// Round 6
// 83.973 us; speedup vs baseline: 2.1835x; 1.7342x over previous
//
#include <hip/hip_runtime.h>

#define N_ARMS   2048
#define NTHREADS 256
#define EPB      8      // elements per thread: 256*8 = 2048
#define N_ITER   200
#define KBUDGET  40.0f

// ---------- DPP wave64 reductions (VALU-only; no LDS-pipe ops) ----------
template <int CTRL>
__device__ __forceinline__ float dpp_mov0(float x) {
    return __int_as_float(__builtin_amdgcn_update_dpp(0, __float_as_int(x), CTRL, 0xf, 0xf, true));
}
__device__ __forceinline__ float wave_sum64(float x) {
    x += dpp_mov0<0x111>(x);   // row_shr:1
    x += dpp_mov0<0x112>(x);   // row_shr:2
    x += dpp_mov0<0x114>(x);   // row_shr:4
    x += dpp_mov0<0x118>(x);   // row_shr:8
    x += dpp_mov0<0x142>(x);   // row_bcast:15
    x += dpp_mov0<0x143>(x);   // row_bcast:31 -> lane 63 holds wave total
    return __int_as_float(__builtin_amdgcn_readlane(__float_as_int(x), 63));
}
__device__ __forceinline__ float wave_max64(float x) {
    x = fmaxf(x, dpp_mov0<0x111>(x));
    x = fmaxf(x, dpp_mov0<0x112>(x));
    x = fmaxf(x, dpp_mov0<0x114>(x));
    x = fmaxf(x, dpp_mov0<0x118>(x));
    x = fmaxf(x, dpp_mov0<0x142>(x));
    x = fmaxf(x, dpp_mov0<0x143>(x));
    return __int_as_float(__builtin_amdgcn_readlane(__float_as_int(x), 63));
}

// Cramer solve of 3x3 A x = b.
__device__ __forceinline__ void solve3(
    float a00, float a01, float a02,
    float a10, float a11, float a12,
    float a20, float a21, float a22,
    float b0, float b1, float b2,
    float& x0, float& x1, float& x2)
{
    float M00 = a11 * a22 - a12 * a21;
    float M01 = a10 * a22 - a12 * a20;
    float M02 = a10 * a21 - a11 * a20;
    float det = a00 * M00 - a01 * M01 + a02 * M02;
    float inv = 1.0f / det;
    float N0  = b1 * a22 - a12 * b2;
    float N1  = b1 * a21 - a11 * b2;
    float N2  = a10 * b2 - b1 * a20;
    x0 = (b0 * M00 - a01 * N0 + a02 * N1) * inv;
    x1 = (a00 * N0 - b0 * M01 + a02 * N2) * inv;
    x2 = (a00 * (a11 * b2 - b1 * a21) - a01 * N2 + b0 * M02) * inv;
}

__global__ __launch_bounds__(NTHREADS, 1) void rmab_kernel(
    const float* __restrict__ T, const int* __restrict__ state,
    float* __restrict__ out)
{
    const int b    = blockIdx.x;
    const int tid  = threadIdx.x;
    const int lane = tid & 63;
    const int wid  = tid >> 6;
    const float gd = 0.99f;
    const float K_T = 100.0f * 1.4426950408889634f;  // inv_eps * log2(e)

    const float* Tb  = T + (size_t)b * N_ARMS * 8;
    const int*   stb = state + (size_t)b * N_ARMS;

    float c0r[EPB], c1r[EPB];
    float mt[EPB];                  // (C0n - C1n) * K_T
    float sig[EPB];
    float cmax_local = 0.0f;

    #pragma unroll
    for (int e = 0; e < EPB; ++e) {
        int i = e * NTHREADS + tid;
        const float4* p = (const float4*)(Tb + (size_t)i * 8);
        float4 T0 = p[0];   // t000 t001 t010 t011  (s=0)
        float4 T1 = p[1];   // t100 t101 t110 t111  (s=1)
        int st = stb[i];
        bool s1 = (st != 0);

        float r1y = gd * T0.x - 1.0f, r1z = gd * T0.y;
        float r2y = gd * T0.z - 1.0f, r2z = gd * T0.w;
        float r3y = gd * T1.x,        r3z = gd * T1.y - 1.0f;
        float r4y = gd * T1.z,        r4z = gd * T1.w - 1.0f;

        // state0: A1={r1,r2,r3}, A2={r1,r2,r4}, b={0,0,-1}
        // state1: A1={r3,r4,r1}, A2={r3,r4,r2}, b={-1,-1,0}
        float a01 = s1 ? r3y : r1y, a02 = s1 ? r3z : r1z;
        float a11 = s1 ? r4y : r2y, a12 = s1 ? r4z : r2z;
        float c21 = s1 ? r1y : r3y, c22 = s1 ? r1z : r3z;
        float d21 = s1 ? r2y : r4y, d22 = s1 ? r2z : r4z;
        float bv0 = s1 ? -1.0f : 0.0f;
        float bv1 = s1 ? -1.0f : 0.0f;
        float bv2 = s1 ?  0.0f : -1.0f;

        float x0, x1, x2;
        solve3(1.0f, a01, a02,  0.0f, a11, a12,  1.0f, c21, c22,
               bv0, bv1, bv2, x0, x1, x2);
        float y0, y1u, y2u;
        solve3(1.0f, a01, a02,  0.0f, a11, a12,  0.0f, d21, d22,
               bv0, bv1, bv2, y0, y1u, y2u);

        float p0 = s1 ? T0.x : T1.x;
        float p1 = s1 ? T0.y : T1.y;
        float q0 = s1 ? T0.z : T1.z;
        float q1 = s1 ? T0.w : T1.w;
        float base = s1 ? 0.0f : 1.0f;
        float lhs = x0 + base + gd * (p0 * x1 + p1 * x2);
        float rhs = base + gd * (q0 * x1 + q1 * x2);
        float w  = (lhs >= rhs) ? x0 : y0;

        float sc = -w;
        float c0 = sc * sc;
        float c1 = (sc - 1.0f) * (sc - 1.0f);
        c0r[e] = c0; c1r[e] = c1;
        cmax_local = fmaxf(cmax_local, fmaxf(c0, c1));
    }

    // ---- block max reduce for C normalization ----
    __shared__ __align__(16) float red[2][4];
    float wm = wave_max64(cmax_local);
    if (lane == 63) red[0][wid] = wm;
    __syncthreads();
    float Cm = fmaxf(fmaxf(red[0][0], red[0][1]), fmaxf(red[0][2], red[0][3]));
    __syncthreads();

    float invCm = K_T / Cm;
    #pragma unroll
    for (int e = 0; e < EPB; ++e) {
        mt[e] = (c0r[e] - c1r[e]) * invCm;
    }

    // ---- collapsed Sinkhorn in log2 domain, with bit-stable early exit:
    //   S = sum_i 1/(1 + 2^(mt_i - u2)),  u2 += log2(2048-S) - log2(S) + log2(40/2008)
    // The recurrence is a 1-D contraction; once |du| < 1e-5 the remaining
    // iterations perturb the output by < 4e-5 (threshold is 2e-2). du is
    // computed identically by all threads from the same LDS S -> uniform break.
    const float DU_C = -5.6496276f;          // log2(40/2008)
    float u2 = 0.0f;
    float S  = 0.0f;
    for (int it = 0; it < N_ITER; ++it) {
        float a0 = 0.0f, a1 = 0.0f, a2 = 0.0f, a3 = 0.0f;
        #pragma unroll
        for (int e = 0; e < EPB; e += 4) {
            float ex0 = __builtin_amdgcn_exp2f(mt[e]     - u2);
            float ex1 = __builtin_amdgcn_exp2f(mt[e + 1] - u2);
            float ex2 = __builtin_amdgcn_exp2f(mt[e + 2] - u2);
            float ex3 = __builtin_amdgcn_exp2f(mt[e + 3] - u2);
            float s0 = __builtin_amdgcn_rcpf(1.0f + ex0);
            float s1v = __builtin_amdgcn_rcpf(1.0f + ex1);
            float s2 = __builtin_amdgcn_rcpf(1.0f + ex2);
            float s3 = __builtin_amdgcn_rcpf(1.0f + ex3);
            sig[e] = s0; sig[e + 1] = s1v; sig[e + 2] = s2; sig[e + 3] = s3;
            a0 += s0; a1 += s1v; a2 += s2; a3 += s3;
        }
        float local = (a0 + a1) + (a2 + a3);
        float wsum = wave_sum64(local);
        int buf = it & 1;
        if (lane == 63) red[buf][wid] = wsum;
        __syncthreads();
        float4 pr = *(const float4*)red[buf];
        S = (pr.x + pr.y) + (pr.z + pr.w);
        if (it == N_ITER - 1) break;
        float du = (__log2f(2048.0f - S) - __log2f(S)) + DU_C;
        u2 += du;
        if (__builtin_fabsf(du) < 1e-5f) break;   // converged: fixed point within fp32 noise
        // red[] is double-buffered: next write to this buf is 2 barriers away
    }

    // out_i = n * Gamma_i0 = (40/S) * sigmoid_i at the final iterate
    float scale = KBUDGET / S;
    float* ob = out + (size_t)b * N_ARMS;
    #pragma unroll
    for (int e = 0; e < EPB; ++e) {
        ob[e * NTHREADS + tid] = scale * sig[e];
    }
}

extern "C" void kernel_launch(void* const* d_in, const int* in_sizes, int n_in,
                              void* d_out, int out_size, void* d_ws, size_t ws_size,
                              hipStream_t stream) {
    const float* T     = (const float*)d_in[0];
    const int*   state = (const int*)d_in[1];
    float*       out   = (float*)d_out;
    int B = in_sizes[1] / N_ARMS;   // state is [B, N]
    rmab_kernel<<<dim3(B), dim3(NTHREADS), 0, stream>>>(T, state, out);
}

// Round 7
// 64.788 us; speedup vs baseline: 2.8301x; 1.2961x over previous
//
#include <hip/hip_runtime.h>

#define N_ARMS   2048
#define NTHREADS 256
#define EPB      8      // elements per thread: 256*8 = 2048
#define N_ITER   200
#define KBUDGET  40.0f

// ---------- DPP wave64 reductions (VALU-only; no LDS-pipe ops) ----------
template <int CTRL>
__device__ __forceinline__ float dpp_mov0(float x) {
    return __int_as_float(__builtin_amdgcn_update_dpp(0, __float_as_int(x), CTRL, 0xf, 0xf, true));
}
__device__ __forceinline__ float wave_sum64(float x) {
    x += dpp_mov0<0x111>(x);   // row_shr:1
    x += dpp_mov0<0x112>(x);   // row_shr:2
    x += dpp_mov0<0x114>(x);   // row_shr:4
    x += dpp_mov0<0x118>(x);   // row_shr:8
    x += dpp_mov0<0x142>(x);   // row_bcast:15
    x += dpp_mov0<0x143>(x);   // row_bcast:31 -> lane 63 holds wave total
    return __int_as_float(__builtin_amdgcn_readlane(__float_as_int(x), 63));
}
__device__ __forceinline__ float wave_max64(float x) {
    x = fmaxf(x, dpp_mov0<0x111>(x));
    x = fmaxf(x, dpp_mov0<0x112>(x));
    x = fmaxf(x, dpp_mov0<0x114>(x));
    x = fmaxf(x, dpp_mov0<0x118>(x));
    x = fmaxf(x, dpp_mov0<0x142>(x));
    x = fmaxf(x, dpp_mov0<0x143>(x));
    return __int_as_float(__builtin_amdgcn_readlane(__float_as_int(x), 63));
}

// Cramer solve of 3x3 A x = b.
__device__ __forceinline__ void solve3(
    float a00, float a01, float a02,
    float a10, float a11, float a12,
    float a20, float a21, float a22,
    float b0, float b1, float b2,
    float& x0, float& x1, float& x2)
{
    float M00 = a11 * a22 - a12 * a21;
    float M01 = a10 * a22 - a12 * a20;
    float M02 = a10 * a21 - a11 * a20;
    float det = a00 * M00 - a01 * M01 + a02 * M02;
    float inv = 1.0f / det;
    float N0  = b1 * a22 - a12 * b2;
    float N1  = b1 * a21 - a11 * b2;
    float N2  = a10 * b2 - b1 * a20;
    x0 = (b0 * M00 - a01 * N0 + a02 * N1) * inv;
    x1 = (a00 * N0 - b0 * M01 + a02 * N2) * inv;
    x2 = (a00 * (a11 * b2 - b1 * a21) - a01 * N2 + b0 * M02) * inv;
}

__global__ __launch_bounds__(NTHREADS, 1) void rmab_kernel(
    const float* __restrict__ T, const int* __restrict__ state,
    float* __restrict__ out)
{
    const int b    = blockIdx.x;
    const int tid  = threadIdx.x;
    const int lane = tid & 63;
    const int wid  = tid >> 6;
    const float gd = 0.99f;
    const float K_T = 100.0f * 1.4426950408889634f;  // inv_eps * log2(e)

    const float* Tb  = T + (size_t)b * N_ARMS * 8;
    const int*   stb = state + (size_t)b * N_ARMS;

    float c0r[EPB], c1r[EPB];
    float mt[EPB];                  // (C0n - C1n) * K_T
    float sig[EPB];
    float cmax_local = 0.0f;

    #pragma unroll
    for (int e = 0; e < EPB; ++e) {
        int i = e * NTHREADS + tid;
        const float4* p = (const float4*)(Tb + (size_t)i * 8);
        float4 T0 = p[0];   // t000 t001 t010 t011  (s=0)
        float4 T1 = p[1];   // t100 t101 t110 t111  (s=1)
        int st = stb[i];
        bool s1 = (st != 0);

        float r1y = gd * T0.x - 1.0f, r1z = gd * T0.y;
        float r2y = gd * T0.z - 1.0f, r2z = gd * T0.w;
        float r3y = gd * T1.x,        r3z = gd * T1.y - 1.0f;
        float r4y = gd * T1.z,        r4z = gd * T1.w - 1.0f;

        // state0: A1={r1,r2,r3}, A2={r1,r2,r4}, b={0,0,-1}
        // state1: A1={r3,r4,r1}, A2={r3,r4,r2}, b={-1,-1,0}
        float a01 = s1 ? r3y : r1y, a02 = s1 ? r3z : r1z;
        float a11 = s1 ? r4y : r2y, a12 = s1 ? r4z : r2z;
        float c21 = s1 ? r1y : r3y, c22 = s1 ? r1z : r3z;
        float d21 = s1 ? r2y : r4y, d22 = s1 ? r2z : r4z;
        float bv0 = s1 ? -1.0f : 0.0f;
        float bv1 = s1 ? -1.0f : 0.0f;
        float bv2 = s1 ?  0.0f : -1.0f;

        float x0, x1, x2;
        solve3(1.0f, a01, a02,  0.0f, a11, a12,  1.0f, c21, c22,
               bv0, bv1, bv2, x0, x1, x2);
        float y0, y1u, y2u;
        solve3(1.0f, a01, a02,  0.0f, a11, a12,  0.0f, d21, d22,
               bv0, bv1, bv2, y0, y1u, y2u);

        float p0 = s1 ? T0.x : T1.x;
        float p1 = s1 ? T0.y : T1.y;
        float q0 = s1 ? T0.z : T1.z;
        float q1 = s1 ? T0.w : T1.w;
        float base = s1 ? 0.0f : 1.0f;
        float lhs = x0 + base + gd * (p0 * x1 + p1 * x2);
        float rhs = base + gd * (q0 * x1 + q1 * x2);
        float w  = (lhs >= rhs) ? x0 : y0;

        float sc = -w;
        float c0 = sc * sc;
        float c1 = (sc - 1.0f) * (sc - 1.0f);
        c0r[e] = c0; c1r[e] = c1;
        cmax_local = fmaxf(cmax_local, fmaxf(c0, c1));
    }

    // ---- block max reduce for C normalization ----
    __shared__ __align__(16) float redS[2][4];
    __shared__ __align__(16) float redD[2][4];
    float wm = wave_max64(cmax_local);
    if (lane == 63) redS[0][wid] = wm;
    __syncthreads();
    float Cm = fmaxf(fmaxf(redS[0][0], redS[0][1]), fmaxf(redS[0][2], redS[0][3]));
    __syncthreads();

    float invCm = K_T / Cm;
    #pragma unroll
    for (int e = 0; e < EPB; ++e) {
        mt[e] = (c0r[e] - c1r[e]) * invCm;
    }

    // ---- scalar root-solve (collapsed Sinkhorn): find u2 with S(u2) = 40,
    //   S = sum_i 1/(1 + 2^(mt_i - u2)).  S is strictly increasing in u2.
    // Newton (quadratic) with bisection bracket; fallback = the reference's own
    // Picard step  du = log2((2048-S)/S) + log2(40/2008)  (linear rate, proven
    // convergent on this data by rounds 4-6). Both converge to the same root;
    // round 6 showed output depends only on the root (absmax at bf16 floor).
    const float DU_C = -5.6496276f;          // log2(40/2008)
    const float LN2  = 0.6931472f;
    float u2 = 0.0f;
    float S  = 0.0f;
    float lo = -3.4e38f, hi = 3.4e38f;
    for (int it = 0; it < N_ITER; ++it) {
        float a0 = 0.0f, a1 = 0.0f;     // sigma partial sums
        float d0 = 0.0f, d1 = 0.0f;     // sigma(1-sigma) partial sums
        #pragma unroll
        for (int e = 0; e < EPB; e += 2) {
            float ex0 = __builtin_amdgcn_exp2f(mt[e]     - u2);
            float ex1 = __builtin_amdgcn_exp2f(mt[e + 1] - u2);
            float s0 = __builtin_amdgcn_rcpf(1.0f + ex0);
            float s1v = __builtin_amdgcn_rcpf(1.0f + ex1);
            sig[e] = s0; sig[e + 1] = s1v;
            a0 += s0;  a1 += s1v;
            d0 = __builtin_fmaf(-s0, s0, d0 + s0);     // += s0 - s0^2
            d1 = __builtin_fmaf(-s1v, s1v, d1 + s1v);
        }
        float wS = wave_sum64(a0 + a1);
        float wD = wave_sum64(d0 + d1);
        int buf = it & 1;
        if (lane == 63) { redS[buf][wid] = wS; redD[buf][wid] = wD; }
        __syncthreads();
        float4 pS = *(const float4*)redS[buf];
        float4 pD = *(const float4*)redD[buf];
        S = (pS.x + pS.y) + (pS.z + pS.w);
        if (it == N_ITER - 1) break;
        float D = (pD.x + pD.y) + (pD.z + pD.w);

        // bracket update at the evaluated point
        float ue = u2;
        if (S < KBUDGET) lo = fmaxf(lo, ue); else hi = fminf(hi, ue);

        // Picard step (clamped S keeps logs finite even if saturated)
        float Sc = fminf(fmaxf(S, 1e-4f), 2047.9f);
        float duP = (__log2f(2048.0f - Sc) - __log2f(Sc)) + DU_C;
        // Newton step
        float duN = (KBUDGET - S) * __builtin_amdgcn_rcpf(LN2 * D);
        float cand = u2 + duN;
        bool ok = (D > 1e-20f) && (cand > lo) && (cand < hi);
        float du = ok ? duN : duP;
        u2 += du;
        if (__builtin_fabsf(du) < 1e-5f) break;   // converged
        // redS/redD double-buffered: next write to this buf is 2 barriers away
    }

    // out_i = n * Gamma_i0 = (40/S) * sigmoid_i at the final iterate
    float scale = KBUDGET / S;
    float* ob = out + (size_t)b * N_ARMS;
    #pragma unroll
    for (int e = 0; e < EPB; ++e) {
        ob[e * NTHREADS + tid] = scale * sig[e];
    }
}

extern "C" void kernel_launch(void* const* d_in, const int* in_sizes, int n_in,
                              void* d_out, int out_size, void* d_ws, size_t ws_size,
                              hipStream_t stream) {
    const float* T     = (const float*)d_in[0];
    const int*   state = (const int*)d_in[1];
    float*       out   = (float*)d_out;
    int B = in_sizes[1] / N_ARMS;   // state is [B, N]
    rmab_kernel<<<dim3(B), dim3(NTHREADS), 0, stream>>>(T, state, out);
}

// Round 8
// 64.313 us; speedup vs baseline: 2.8510x; 1.0074x over previous
//
#include <hip/hip_runtime.h>

#define N_ARMS   2048
#define NTHREADS 512
#define NWAVES   (NTHREADS / 64)
#define EPB      4      // elements per thread: 512*4 = 2048
#define N_ITER   200
#define KBUDGET  40.0f

// ---------- DPP wave64 reductions (VALU-only; no LDS-pipe ops) ----------
template <int CTRL>
__device__ __forceinline__ float dpp_mov0(float x) {
    return __int_as_float(__builtin_amdgcn_update_dpp(0, __float_as_int(x), CTRL, 0xf, 0xf, true));
}
__device__ __forceinline__ float wave_sum64(float x) {
    x += dpp_mov0<0x111>(x);   // row_shr:1
    x += dpp_mov0<0x112>(x);   // row_shr:2
    x += dpp_mov0<0x114>(x);   // row_shr:4
    x += dpp_mov0<0x118>(x);   // row_shr:8
    x += dpp_mov0<0x142>(x);   // row_bcast:15
    x += dpp_mov0<0x143>(x);   // row_bcast:31 -> lane 63 holds wave total
    return __int_as_float(__builtin_amdgcn_readlane(__float_as_int(x), 63));
}
__device__ __forceinline__ float wave_max64(float x) {
    x = fmaxf(x, dpp_mov0<0x111>(x));
    x = fmaxf(x, dpp_mov0<0x112>(x));
    x = fmaxf(x, dpp_mov0<0x114>(x));
    x = fmaxf(x, dpp_mov0<0x118>(x));
    x = fmaxf(x, dpp_mov0<0x142>(x));
    x = fmaxf(x, dpp_mov0<0x143>(x));
    return __int_as_float(__builtin_amdgcn_readlane(__float_as_int(x), 63));
}

__global__ __launch_bounds__(NTHREADS, 1) void rmab_kernel(
    const float* __restrict__ T, const int* __restrict__ state,
    float* __restrict__ out)
{
    const int b    = blockIdx.x;
    const int tid  = threadIdx.x;
    const int lane = tid & 63;
    const int wid  = tid >> 6;
    const float gd = 0.99f;
    const float K_T = 100.0f * 1.4426950408889634f;  // inv_eps * log2(e)

    const float* Tb  = T + (size_t)b * N_ARMS * 8;
    const int*   stb = state + (size_t)b * N_ARMS;

    float c0r[EPB], c1r[EPB];
    float mt[EPB];                  // (C0n - C1n) * K_T
    float sig[EPB];
    float cmax_local = 0.0f;

    #pragma unroll
    for (int e = 0; e < EPB; ++e) {
        int i = e * NTHREADS + tid;
        const float4* p = (const float4*)(Tb + (size_t)i * 8);
        float4 T0 = p[0];   // t000 t001 t010 t011  (s=0)
        float4 T1 = p[1];   // t100 t101 t110 t111  (s=1)
        int st = stb[i];
        bool s1 = (st != 0);

        float r1y = gd * T0.x - 1.0f, r1z = gd * T0.y;
        float r2y = gd * T0.z - 1.0f, r2z = gd * T0.w;
        float r3y = gd * T1.x,        r3z = gd * T1.y - 1.0f;
        float r4y = gd * T1.z,        r4z = gd * T1.w - 1.0f;

        // state0: A1={r1,r2,r3}, A2={r1,r2,r4}, b={0,0,-1}
        // state1: A1={r3,r4,r1}, A2={r3,r4,r2}, b={-1,-1,0}
        // Rows 0 (leading 1) and 1 (leading 0) are shared between A1 and A2;
        // A1's row2 has leading 1, A2's row2 leading 0 -> eliminate x0 and
        // solve a 2x2 per system instead of two 3x3 Cramers.
        float a01 = s1 ? r3y : r1y, a02 = s1 ? r3z : r1z;   // row0 y,z
        float a11 = s1 ? r4y : r2y, a12 = s1 ? r4z : r2z;   // row1 y,z
        float c21 = s1 ? r1y : r3y, c22 = s1 ? r1z : r3z;   // A1 row2 y,z
        float d21 = s1 ? r2y : r4y, d22 = s1 ? r2z : r4z;   // A2 row2 y,z
        float bv01 = s1 ? -1.0f : 0.0f;                     // b[0] == b[1]
        float bv2  = s1 ?  0.0f : -1.0f;                    // b[2]

        // A1 solve: row2 - row0 eliminates x0:
        //   (c21-a01) x1 + (c22-a02) x2 = bv2 - bv01 ; a11 x1 + a12 x2 = bv01
        float e21 = c21 - a01, e22 = c22 - a02, r2 = bv2 - bv01;
        float det1 = a11 * e22 - a12 * e21;
        float inv1 = 1.0f / det1;
        float x1 = (bv01 * e22 - a12 * r2) * inv1;
        float x2 = (a11 * r2 - bv01 * e21) * inv1;
        float x0 = bv01 - a01 * x1 - a02 * x2;

        // A2 solve: row2 already x0-free:
        //   a11 y1 + a12 y2 = bv01 ; d21 y1 + d22 y2 = bv2
        float det2 = a11 * d22 - a12 * d21;
        float inv2 = 1.0f / det2;
        float y1 = (bv01 * d22 - a12 * bv2) * inv2;
        float y2 = (a11 * bv2 - bv01 * d21) * inv2;
        float y0 = bv01 - a01 * y1 - a02 * y2;

        // m condition, reference-faithful operand order
        float p0 = s1 ? T0.x : T1.x;
        float p1 = s1 ? T0.y : T1.y;
        float q0 = s1 ? T0.z : T1.z;
        float q1 = s1 ? T0.w : T1.w;
        float base = s1 ? 0.0f : 1.0f;
        float lhs = x0 + base + gd * (p0 * x1 + p1 * x2);
        float rhs = base + gd * (q0 * x1 + q1 * x2);
        float w  = (lhs >= rhs) ? x0 : y0;

        float sc = -w;
        float c0 = sc * sc;
        float c1 = (sc - 1.0f) * (sc - 1.0f);
        c0r[e] = c0; c1r[e] = c1;
        cmax_local = fmaxf(cmax_local, fmaxf(c0, c1));
    }

    // ---- block max reduce for C normalization ----
    __shared__ __align__(16) float redS[2][NWAVES];
    __shared__ __align__(16) float redD[2][NWAVES];
    float wm = wave_max64(cmax_local);
    if (lane == 63) redS[0][wid] = wm;
    __syncthreads();
    float Cm = redS[0][0];
    #pragma unroll
    for (int wv = 1; wv < NWAVES; ++wv) Cm = fmaxf(Cm, redS[0][wv]);
    __syncthreads();

    float invCm = K_T / Cm;
    #pragma unroll
    for (int e = 0; e < EPB; ++e) {
        mt[e] = (c0r[e] - c1r[e]) * invCm;
    }

    // ---- scalar root-solve (collapsed Sinkhorn): find u2 with S(u2) = 40,
    //   S = sum_i 1/(1 + 2^(mt_i - u2)), strictly increasing in u2.
    // Newton (quadratic) w/ bisection bracket; fallback = reference's Picard
    // step (proven convergent rounds 4-6). Output depends only on the root.
    const float DU_C = -5.6496276f;          // log2(40/2008)
    const float LN2  = 0.6931472f;
    float u2 = 0.0f;
    float S  = 0.0f;
    float lo = -3.4e38f, hi = 3.4e38f;
    for (int it = 0; it < N_ITER; ++it) {
        float a0 = 0.0f, a1 = 0.0f;     // sigma partial sums
        float d0 = 0.0f, d1 = 0.0f;     // sigma(1-sigma) partial sums
        #pragma unroll
        for (int e = 0; e < EPB; e += 2) {
            float ex0 = __builtin_amdgcn_exp2f(mt[e]     - u2);
            float ex1 = __builtin_amdgcn_exp2f(mt[e + 1] - u2);
            float s0 = __builtin_amdgcn_rcpf(1.0f + ex0);
            float s1v = __builtin_amdgcn_rcpf(1.0f + ex1);
            sig[e] = s0; sig[e + 1] = s1v;
            a0 += s0;  a1 += s1v;
            d0 = __builtin_fmaf(-s0, s0, d0 + s0);     // += s0 - s0^2
            d1 = __builtin_fmaf(-s1v, s1v, d1 + s1v);
        }
        float wS = wave_sum64(a0 + a1);
        float wD = wave_sum64(d0 + d1);
        int buf = it & 1;
        if (lane == 63) { redS[buf][wid] = wS; redD[buf][wid] = wD; }
        __syncthreads();
        S = redS[buf][0];
        float D = redD[buf][0];
        #pragma unroll
        for (int wv = 1; wv < NWAVES; ++wv) { S += redS[buf][wv]; D += redD[buf][wv]; }
        if (it == N_ITER - 1) break;

        // bracket update at the evaluated point
        if (S < KBUDGET) lo = fmaxf(lo, u2); else hi = fminf(hi, u2);

        // Picard step (clamped S keeps logs finite even if saturated)
        float Sc = fminf(fmaxf(S, 1e-4f), 2047.9f);
        float duP = (__log2f(2048.0f - Sc) - __log2f(Sc)) + DU_C;
        // Newton step
        float duN = (KBUDGET - S) * __builtin_amdgcn_rcpf(LN2 * D);
        float cand = u2 + duN;
        bool ok = (D > 1e-20f) && (cand > lo) && (cand < hi);
        float du = ok ? duN : duP;
        u2 += du;
        if (__builtin_fabsf(du) < 1e-5f) break;   // converged
        // redS/redD double-buffered: next write to this buf is 2 barriers away
    }

    // out_i = n * Gamma_i0 = (40/S) * sigmoid_i at the final iterate
    float scale = KBUDGET / S;
    float* ob = out + (size_t)b * N_ARMS;
    #pragma unroll
    for (int e = 0; e < EPB; ++e) {
        ob[e * NTHREADS + tid] = scale * sig[e];
    }
}

extern "C" void kernel_launch(void* const* d_in, const int* in_sizes, int n_in,
                              void* d_out, int out_size, void* d_ws, size_t ws_size,
                              hipStream_t stream) {
    const float* T     = (const float*)d_in[0];
    const int*   state = (const int*)d_in[1];
    float*       out   = (float*)d_out;
    int B = in_sizes[1] / N_ARMS;   // state is [B, N]
    rmab_kernel<<<dim3(B), dim3(NTHREADS), 0, stream>>>(T, state, out);
}

// Round 9
// 62.138 us; speedup vs baseline: 2.9508x; 1.0350x over previous
//
#include <hip/hip_runtime.h>

#define N_ARMS   2048
#define NTHREADS 512
#define NWAVES   (NTHREADS / 64)
#define EPB      4      // elements per thread: 512*4 = 2048
#define N_ITER   200
#define KBUDGET  40.0f

// ---------- DPP wave64 reductions (VALU-only; no LDS-pipe ops) ----------
template <int CTRL>
__device__ __forceinline__ float dpp_mov0(float x) {
    return __int_as_float(__builtin_amdgcn_update_dpp(0, __float_as_int(x), CTRL, 0xf, 0xf, true));
}
__device__ __forceinline__ float wave_sum64(float x) {
    x += dpp_mov0<0x111>(x);   // row_shr:1
    x += dpp_mov0<0x112>(x);   // row_shr:2
    x += dpp_mov0<0x114>(x);   // row_shr:4
    x += dpp_mov0<0x118>(x);   // row_shr:8
    x += dpp_mov0<0x142>(x);   // row_bcast:15
    x += dpp_mov0<0x143>(x);   // row_bcast:31 -> lane 63 holds wave total
    return __int_as_float(__builtin_amdgcn_readlane(__float_as_int(x), 63));
}
__device__ __forceinline__ float wave_max64(float x) {
    x = fmaxf(x, dpp_mov0<0x111>(x));
    x = fmaxf(x, dpp_mov0<0x112>(x));
    x = fmaxf(x, dpp_mov0<0x114>(x));
    x = fmaxf(x, dpp_mov0<0x118>(x));
    x = fmaxf(x, dpp_mov0<0x142>(x));
    x = fmaxf(x, dpp_mov0<0x143>(x));
    return __int_as_float(__builtin_amdgcn_readlane(__float_as_int(x), 63));
}

__global__ __launch_bounds__(NTHREADS, 1) void rmab_kernel(
    const float* __restrict__ T, const int* __restrict__ state,
    float* __restrict__ out)
{
    const int b    = blockIdx.x;
    const int tid  = threadIdx.x;
    const int lane = tid & 63;
    const int wid  = tid >> 6;
    const float gd = 0.99f;
    const float K_T = 100.0f * 1.4426950408889634f;  // inv_eps * log2(e)

    const float* Tb  = T + (size_t)b * N_ARMS * 8;
    const int*   stb = state + (size_t)b * N_ARMS;

    float dcr[EPB];                 // c0 - c1 (raw cost difference)
    float mt[EPB];                  // (C0n - C1n) * K_T
    float sig[EPB];
    float cmax_local = 0.0f;
    float dsum_local = 0.0f, dsq_local = 0.0f;

    #pragma unroll
    for (int e = 0; e < EPB; ++e) {
        int i = e * NTHREADS + tid;
        const float4* p = (const float4*)(Tb + (size_t)i * 8);
        float4 T0 = p[0];   // t000 t001 t010 t011  (s=0)
        float4 T1 = p[1];   // t100 t101 t110 t111  (s=1)
        int st = stb[i];
        bool s1 = (st != 0);

        float r1y = gd * T0.x - 1.0f, r1z = gd * T0.y;
        float r2y = gd * T0.z - 1.0f, r2z = gd * T0.w;
        float r3y = gd * T1.x,        r3z = gd * T1.y - 1.0f;
        float r4y = gd * T1.z,        r4z = gd * T1.w - 1.0f;

        // state0: A1={r1,r2,r3}, A2={r1,r2,r4}, b={0,0,-1}
        // state1: A1={r3,r4,r1}, A2={r3,r4,r2}, b={-1,-1,0}
        // Rows 0/1 shared; eliminate x0 -> one 2x2 per system.
        float a01 = s1 ? r3y : r1y, a02 = s1 ? r3z : r1z;
        float a11 = s1 ? r4y : r2y, a12 = s1 ? r4z : r2z;
        float c21 = s1 ? r1y : r3y, c22 = s1 ? r1z : r3z;
        float d21 = s1 ? r2y : r4y, d22 = s1 ? r2z : r4z;
        float bv01 = s1 ? -1.0f : 0.0f;
        float bv2  = s1 ?  0.0f : -1.0f;

        float e21 = c21 - a01, e22 = c22 - a02, r2 = bv2 - bv01;
        float det1 = a11 * e22 - a12 * e21;
        float inv1 = 1.0f / det1;
        float x1 = (bv01 * e22 - a12 * r2) * inv1;
        float x2 = (a11 * r2 - bv01 * e21) * inv1;
        float x0 = bv01 - a01 * x1 - a02 * x2;

        float det2 = a11 * d22 - a12 * d21;
        float inv2 = 1.0f / det2;
        float y1 = (bv01 * d22 - a12 * bv2) * inv2;
        float y2 = (a11 * bv2 - bv01 * d21) * inv2;
        float y0 = bv01 - a01 * y1 - a02 * y2;

        // m condition, reference-faithful operand order
        float p0 = s1 ? T0.x : T1.x;
        float p1 = s1 ? T0.y : T1.y;
        float q0 = s1 ? T0.z : T1.z;
        float q1 = s1 ? T0.w : T1.w;
        float base = s1 ? 0.0f : 1.0f;
        float lhs = x0 + base + gd * (p0 * x1 + p1 * x2);
        float rhs = base + gd * (q0 * x1 + q1 * x2);
        float w  = (lhs >= rhs) ? x0 : y0;

        float sc = -w;
        float c0 = sc * sc;
        float c1 = (sc - 1.0f) * (sc - 1.0f);
        float d  = c0 - c1;
        dcr[e] = d;
        cmax_local = fmaxf(cmax_local, fmaxf(c0, c1));
        dsum_local += d;
        dsq_local  = __builtin_fmaf(d, d, dsq_local);
    }

    // ---- fused block reduce: max(c), sum(d), sum(d^2) — one barrier ----
    __shared__ __align__(16) float redS[2][NWAVES];
    __shared__ __align__(16) float redD[2][NWAVES];
    __shared__ __align__(16) float redM[NWAVES];
    float wm = wave_max64(cmax_local);
    float ws = wave_sum64(dsum_local);
    float wq = wave_sum64(dsq_local);
    if (lane == 63) { redM[wid] = wm; redS[0][wid] = ws; redD[0][wid] = wq; }
    __syncthreads();
    float Cm = redM[0], Sd = redS[0][0], Sq = redD[0][0];
    #pragma unroll
    for (int wv = 1; wv < NWAVES; ++wv) {
        Cm = fmaxf(Cm, redM[wv]); Sd += redS[0][wv]; Sq += redD[0][wv];
    }
    __syncthreads();

    float invCm = K_T / Cm;
    #pragma unroll
    for (int e = 0; e < EPB; ++e) {
        mt[e] = dcr[e] * invCm;
    }

    // Gaussian-quantile init: root u* is where S ~= 40 of 2048 sigmoids are on,
    // i.e. ~1.95th percentile of mt. u0 = mu - 2.065*sigma (in mt units).
    const float INV_N = 1.0f / 2048.0f;
    float mu_d  = Sd * INV_N;
    float var_d = fmaxf(Sq * INV_N - mu_d * mu_d, 0.0f);
    float u2 = (mu_d - 2.065f * __builtin_amdgcn_sqrtf(var_d)) * invCm;

    // ---- scalar root-solve: S(u2) = 40, S = sum_i 1/(1 + 2^(mt_i - u2)).
    // Newton (quadratic) w/ bisection bracket; Picard fallback (reference's own
    // step, proven convergent rounds 4-6). Output depends only on the root.
    const float DU_C = -5.6496276f;          // log2(40/2008)
    const float LN2  = 0.6931472f;
    float S  = 0.0f;
    float lo = -3.4e38f, hi = 3.4e38f;
    for (int it = 0; it < N_ITER; ++it) {
        float a0 = 0.0f, a1 = 0.0f;     // sigma partial sums
        float d0 = 0.0f, d1 = 0.0f;     // sigma(1-sigma) partial sums
        #pragma unroll
        for (int e = 0; e < EPB; e += 2) {
            float ex0 = __builtin_amdgcn_exp2f(mt[e]     - u2);
            float ex1 = __builtin_amdgcn_exp2f(mt[e + 1] - u2);
            float s0 = __builtin_amdgcn_rcpf(1.0f + ex0);
            float s1v = __builtin_amdgcn_rcpf(1.0f + ex1);
            sig[e] = s0; sig[e + 1] = s1v;
            a0 += s0;  a1 += s1v;
            d0 = __builtin_fmaf(-s0, s0, d0 + s0);     // += s0 - s0^2
            d1 = __builtin_fmaf(-s1v, s1v, d1 + s1v);
        }
        float wS = wave_sum64(a0 + a1);
        float wD = wave_sum64(d0 + d1);
        int buf = it & 1;
        if (lane == 63) { redS[buf][wid] = wS; redD[buf][wid] = wD; }
        __syncthreads();
        S = redS[buf][0];
        float D = redD[buf][0];
        #pragma unroll
        for (int wv = 1; wv < NWAVES; ++wv) { S += redS[buf][wv]; D += redD[buf][wv]; }
        if (it == N_ITER - 1) break;

        // bracket update at the evaluated point
        if (S < KBUDGET) lo = fmaxf(lo, u2); else hi = fminf(hi, u2);

        // Picard step (clamped S keeps logs finite even if saturated)
        float Sc = fminf(fmaxf(S, 1e-4f), 2047.9f);
        float duP = (__log2f(2048.0f - Sc) - __log2f(Sc)) + DU_C;
        // Newton step
        float duN = (KBUDGET - S) * __builtin_amdgcn_rcpf(LN2 * D);
        float cand = u2 + duN;
        bool ok = (D > 1e-20f) && (cand > lo) && (cand < hi);
        float du = ok ? duN : duP;
        u2 += du;
        if (__builtin_fabsf(du) < 1e-3f) break;   // converged (output sens ~0.17/unit)
        // redS/redD double-buffered: next write to this buf is 2 barriers away
    }

    // out_i = n * Gamma_i0 = (40/S) * sigmoid_i at the final iterate
    float scale = KBUDGET / S;
    float* ob = out + (size_t)b * N_ARMS;
    #pragma unroll
    for (int e = 0; e < EPB; ++e) {
        ob[e * NTHREADS + tid] = scale * sig[e];
    }
}

extern "C" void kernel_launch(void* const* d_in, const int* in_sizes, int n_in,
                              void* d_out, int out_size, void* d_ws, size_t ws_size,
                              hipStream_t stream) {
    const float* T     = (const float*)d_in[0];
    const int*   state = (const int*)d_in[1];
    float*       out   = (float*)d_out;
    int B = in_sizes[1] / N_ARMS;   // state is [B, N]
    rmab_kernel<<<dim3(B), dim3(NTHREADS), 0, stream>>>(T, state, out);
}